// Round 16
// baseline (64.363 us; speedup 1.0000x reference)
//
#include <hip/hip_runtime.h>

#define NMOL   32
#define NATOM  512
#define NPAIR  32768
#define NB     64
#define HIDDEN 256
#define TOTNATOM (NMOL * NATOM)
#define NSUB   8
#define CAP8   16    // records per (atom, sub-block)
#define ABLK   8     // atoms per gather block
#define SLOTS  128   // LDS record slots per atom

typedef __attribute__((ext_vector_type(8))) short bf16x8;
typedef __attribute__((ext_vector_type(4))) float f32x4;

__device__ __forceinline__ unsigned short f2bf(float x) {   // RNE f32->bf16
    unsigned u = __float_as_uint(x);
    u += 0x7FFFu + ((u >> 16) & 1u);
    return (unsigned short)(u >> 16);
}

// ---------------------------------------------------------------------------
// K1 scatter: 256 blocks (mol x sub) x 1024 thr, 4 pairs/thread.
// R16: cart/species read DIRECT from global (6KB/mol -> L1-resident after
// warmup; VMEM pipe, deep queue) instead of LDS staging -- the 6 random
// ds_reads/pair contended with the 3 tv ds_adds on the CU's single DS pipe.
// LDS now 8KB (tv + lcnt only). Block 0 zeroes dipole.
// ---------------------------------------------------------------------------
__global__ __launch_bounds__(1024) void scatter_kernel(
    const float* __restrict__ cart, const float* __restrict__ shifts,
    const int* __restrict__ species, const int* __restrict__ atom_index,
    unsigned* __restrict__ cnt8, float2* __restrict__ rec,
    float* __restrict__ tv_part, float* __restrict__ dipole, int ndip)
{
    __shared__ float    tv_sc[NATOM * 3];   // 6 KB
    __shared__ unsigned lcnt[NATOM];        // 2 KB
    const int tid = threadIdx.x;
    const int b   = blockIdx.x;
    const int mol = b >> 3;
    const int sub = b & 7;

    if (b == 0 && tid < ndip) dipole[tid] = 0.f;

    for (int i = tid; i < NATOM * 3; i += 1024) tv_sc[i] = 0.f;
    if (tid < NATOM) lcnt[tid] = 0u;
    __syncthreads();

    const float* cm = cart + (size_t)mol * NATOM * 3;
    const int*   sp = species + (size_t)mol * NATOM;
    const int* ai0 = atom_index + (size_t)mol * NPAIR;
    const int* ai1 = ai0 + (size_t)NMOL * NPAIR;
    const float* sh = shifts + (size_t)mol * NPAIR * 3;
    const int base = sub * 4096;

#pragma unroll
    for (int k = 0; k < 4; ++k) {
        const int p  = base + k * 1024 + tid;
        const int i0 = ai0[p];
        const int i1 = ai1[p];
        const float sx = sh[p * 3 + 0], sy = sh[p * 3 + 1], sz = sh[p * 3 + 2];
        if (!(sx > -1e10f && sy > -1e10f && sz > -1e10f)) continue;  // masked
        const float dx = cm[i0 * 3 + 0] - cm[i1 * 3 + 0] + sx;   // L1 hits
        const float dy = cm[i0 * 3 + 1] - cm[i1 * 3 + 1] + sy;
        const float dz = cm[i0 * 3 + 2] - cm[i1 * 3 + 2] + sz;
        unsafeAtomicAdd(&tv_sc[i0 * 3 + 0], dx);        // ds_add_f32
        unsafeAtomicAdd(&tv_sc[i0 * 3 + 1], dy);
        unsafeAtomicAdd(&tv_sc[i0 * 3 + 2], dz);
        const float d = sqrtf(dx * dx + dy * dy + dz * dz + 1e-12f);
        if (d < 5.0f) {
            const float fc = 0.5f * (__cosf(0.62831853071795864769f * d) + 1.f);
            // pack spc into fc's low 3 mantissa bits (<=2^-20 rel perturbation)
            const unsigned fb = (__float_as_uint(fc) & ~7u) | (unsigned)sp[i1];
            const unsigned pos = atomicAdd(&lcnt[i0], 1u);   // LDS, native
            if (pos < CAP8)
                rec[((size_t)b * NATOM + i0) * CAP8 + pos] =
                    make_float2(d, __uint_as_float(fb));
        }
    }
    __syncthreads();

    if (tid < NATOM) cnt8[((size_t)mol * NATOM + tid) * NSUB + sub] = lcnt[tid];
    float* tg = tv_part + (size_t)b * NATOM * 3;
    for (int i = tid; i < NATOM * 3; i += 1024) tg[i] = tv_sc[i];
}

// ---------------------------------------------------------------------------
// K2 gather: 2048 blocks x 256 thr, 8 atoms/block. Verbatim R14 (proven).
// Emits density as BF16 rows + summed tv.
// ---------------------------------------------------------------------------
__global__ __launch_bounds__(256) void gather_kernel(
    const unsigned* __restrict__ cnt8, const float2* __restrict__ rec,
    const float* __restrict__ centers, const float* __restrict__ widths,
    const float* __restrict__ c_emb, const float* __restrict__ tv_part,
    unsigned short* __restrict__ dens_bf, float* __restrict__ tvv)
{
    __shared__ float    cemb[8 * NB];          // 2 KB
    __shared__ float2   list[ABLK][SLOTS];     // 8 KB
    __shared__ unsigned scnt[ABLK][NSUB];
    __shared__ unsigned soff[ABLK][NSUB];
    __shared__ unsigned mtot[ABLK];

    const int tid = threadIdx.x;
    const int a0  = blockIdx.x * ABLK;
    const int mol = a0 >> 9;
    const int ra0 = a0 & 511;

    for (int i = tid; i < 8 * NB; i += 256) cemb[i] = c_emb[i];
    if (tid < ABLK * NSUB) {
        const int al = tid >> 3, s = tid & 7;
        scnt[al][s] = cnt8[(size_t)(a0 + al) * NSUB + s];   // coalesced
    }
    __syncthreads();

    if (tid < ABLK) {    // per-atom prefix over 8 segment counts + zero-pad
        unsigned o = 0;
#pragma unroll
        for (int s = 0; s < NSUB; ++s) {
            soff[tid][s] = o;
            o += min(scnt[tid][s], (unsigned)CAP8);
        }
        const unsigned mp = (o + 7u) & ~7u;    // pad to multiple of 8
        mtot[tid] = mp;
        for (unsigned k = o; k < mp; ++k) list[tid][k] = make_float2(0.f, 0.f);
    }
    __syncthreads();

    {   // 256-thread parallel segment copy: 4 threads per (atom, sub) segment
        const int seg = tid >> 2;              // 0..63
        const int prt = tid & 3;
        const int al = seg >> 3, s = seg & 7;
        const int n = (int)min(scnt[al][s], (unsigned)CAP8);
        const float2* src = rec + ((size_t)(mol * NSUB + s) * NATOM + (ra0 + al)) * CAP8;
        float2* dst = &list[al][soff[al][s]];
        const int k0 = prt * 4, k1 = min(k0 + 4, n);
        for (int k = k0; k < k1; ++k) dst[k] = src[k];
    }
    if (tid < ABLK * 3) {                      // tv: sum the 8 block-partials
        const int al = tid / 3, c = tid - al * 3;
        float s = 0.f;
#pragma unroll
        for (int sb = 0; sb < NSUB; ++sb)
            s += tv_part[((size_t)(mol * NSUB + sb) * NATOM + (ra0 + al)) * 3 + c];
        tvv[(size_t)(a0 + al) * 3 + c] = s;
    }
    __syncthreads();

    const int lane = tid & 63;
    const int wave = tid >> 6;
    const float cb   = centers[lane];
    const float nwb2 = -widths[lane] * 1.4426950408889634f;   // fold log2(e)

#define REC1(A, dv, fv) { const unsigned f_ = __float_as_uint(fv);           \
        const float t_ = (dv) - cb;                                          \
        A = fmaf(exp2f(nwb2 * t_ * t_) * __uint_as_float(f_ & ~7u),          \
                 cemb[((f_ & 7u) << 6) | lane], A); }

    for (int al = wave; al < ABLK; al += 4) {  // wave handles 2 atoms
        const int m = (int)mtot[al];
        const float4* l4 = reinterpret_cast<const float4*>(list[al]);
        float acc0 = 0.f, acc1 = 0.f;
        for (int j = 0; j < m; j += 8) {
            const float4 q0 = l4[(j >> 1) + 0];
            const float4 q1 = l4[(j >> 1) + 1];
            const float4 q2 = l4[(j >> 1) + 2];
            const float4 q3 = l4[(j >> 1) + 3];
            REC1(acc0, q0.x, q0.y) REC1(acc1, q0.z, q0.w)
            REC1(acc0, q1.x, q1.y) REC1(acc1, q1.z, q1.w)
            REC1(acc0, q2.x, q2.y) REC1(acc1, q2.z, q2.w)
            REC1(acc0, q3.x, q3.y) REC1(acc1, q3.z, q3.w)
        }
        dens_bf[(size_t)(a0 + al) * NB + lane] = f2bf(acc0 + acc1);
    }
#undef REC1
}

// ---------------------------------------------------------------------------
// K3 nn via MFMA: 1024 blocks x 256 thr, 16 atoms/block.
// R16: regrid from 256x64 (1 block/CU, 1 wave/SIMD -- latency-naked W1
// staging) to 1024x16 (39KB LDS -> 4 blocks/CU, 4 waves/SIMD). Dipole folded
// in via 3 device atomics/block (dipfinal kernel + its launch gap deleted).
// ---------------------------------------------------------------------------
__global__ __launch_bounds__(256) void nnm_kernel(
    const unsigned short* __restrict__ dens_bf, const float* __restrict__ tvv,
    const float* __restrict__ W1, const float* __restrict__ b1,
    const float* __restrict__ W2, const float* __restrict__ b2,
    float* __restrict__ dipole)
{
    __shared__ __align__(16) unsigned short w1t[HIDDEN * 72];  // 36 KB
    __shared__ float b1_l[HIDDEN], w2_l[HIDDEN];
    __shared__ float tv_l[16 * 3];
    __shared__ float sred[4][4][4];            // [wave][fg][i]

    const int tid = threadIdx.x;
    const int a0  = blockIdx.x * 16;
    const int mol = a0 >> 9;

    for (int i = tid; i < NB * HIDDEN; i += 256) {     // stage W1^T as bf16
        const int k = i >> 8, j = i & 255;             // coalesced f32 reads
        w1t[j * 72 + k] = f2bf(W1[i]);
    }
    if (tid < HIDDEN) { b1_l[tid] = b1[tid]; w2_l[tid] = W2[tid]; }
    if (tid < 48) tv_l[tid] = tvv[(size_t)a0 * 3 + tid];
    __syncthreads();

    const int lane = tid & 63;
    const int wave = tid >> 6;
    const int fr   = lane & 15;        // C col (j in tile) / A-B row
    const int fg   = lane >> 4;        // k-group; C rows = fg*4+i

    bf16x8 afr[2];                     // A-frags for the block's 16-atom tile
#pragma unroll
    for (int kk = 0; kk < 2; ++kk)
        afr[kk] = *reinterpret_cast<const bf16x8*>(
            dens_bf + (size_t)(a0 + fr) * NB + kk * 32 + fg * 8);

    float sdip[4] = {0.f, 0.f, 0.f, 0.f};
#pragma unroll
    for (int t = 0; t < 4; ++t) {                      // wave covers 4 N-tiles
        const int nt = wave * 4 + t;
        const bf16x8 bf0 = *reinterpret_cast<const bf16x8*>(
            &w1t[(nt * 16 + fr) * 72 + 0 + fg * 8]);
        const bf16x8 bf1 = *reinterpret_cast<const bf16x8*>(
            &w1t[(nt * 16 + fr) * 72 + 32 + fg * 8]);
        f32x4 acc = {0.f, 0.f, 0.f, 0.f};
        acc = __builtin_amdgcn_mfma_f32_16x16x32_bf16(afr[0], bf0, acc, 0, 0, 0);
        acc = __builtin_amdgcn_mfma_f32_16x16x32_bf16(afr[1], bf1, acc, 0, 0, 0);
        const int j = nt * 16 + fr;
        const float b1v = b1_l[j], w2v = w2_l[j];
#pragma unroll
        for (int i = 0; i < 4; ++i) {                  // silu * W2
            const float h = acc[i] + b1v;
            sdip[i] += (h / (1.f + __expf(-h))) * w2v;
        }
    }
#pragma unroll
    for (int off = 1; off < 16; off <<= 1) {           // reduce over 16 j-cols
#pragma unroll
        for (int i = 0; i < 4; ++i) sdip[i] += __shfl_xor(sdip[i], off);
    }
    if (fr == 0) {
#pragma unroll
        for (int i = 0; i < 4; ++i) sred[wave][fg][i] = sdip[i];
    }
    __syncthreads();

    if (tid < 16) {                                    // atom a = tid
        const int a = tid;
        const float out = sred[0][a >> 2][a & 3] + sred[1][a >> 2][a & 3]
                        + sred[2][a >> 2][a & 3] + sred[3][a >> 2][a & 3]
                        + b2[0];
        float px = out * tv_l[a * 3 + 0];
        float py = out * tv_l[a * 3 + 1];
        float pz = out * tv_l[a * 3 + 2];
#pragma unroll
        for (int off = 8; off; off >>= 1) {
            px += __shfl_down(px, off, 16);
            py += __shfl_down(py, off, 16);
            pz += __shfl_down(pz, off, 16);
        }
        if (a == 0) {
            unsafeAtomicAdd(&dipole[mol * 3 + 0], px);
            unsafeAtomicAdd(&dipole[mol * 3 + 1], py);
            unsafeAtomicAdd(&dipole[mol * 3 + 2], pz);
        }
    }
}

// ---------------------------------------------------------------------------
extern "C" void kernel_launch(void* const* d_in, const int* in_sizes, int n_in,
                              void* d_out, int out_size, void* d_ws, size_t ws_size,
                              hipStream_t stream)
{
    const float* cart       = (const float*)d_in[0];
    const float* shifts     = (const float*)d_in[1];
    const float* centers    = (const float*)d_in[2];
    const float* widths     = (const float*)d_in[3];
    const float* c_emb      = (const float*)d_in[4];
    const float* W1         = (const float*)d_in[5];
    const float* b1         = (const float*)d_in[6];
    const float* W2         = (const float*)d_in[7];
    const float* b2         = (const float*)d_in[8];
    const int*   species    = (const int*)d_in[10];
    const int*   atom_index = (const int*)d_in[11];

    // ws: tv_part(1.5MB) | cnt8(512KB) | tvv(192KB) | dens_bf(2MB) | rec(16MB)
    float*          tv_part = (float*)d_ws;
    unsigned*       cnt8    = (unsigned*)(tv_part + (size_t)NMOL * NSUB * NATOM * 3);
    float*          tvv     = (float*)(cnt8 + (size_t)TOTNATOM * NSUB);
    unsigned short* dens_bf = (unsigned short*)(tvv + (size_t)TOTNATOM * 3);
    float2*         rec     = (float2*)(dens_bf + (size_t)TOTNATOM * NB);
    float*          dipole  = (float*)d_out;

    hipLaunchKernelGGL(scatter_kernel, dim3(NMOL * NSUB), dim3(1024), 0, stream,
                       cart, shifts, species, atom_index, cnt8, rec, tv_part,
                       dipole, out_size);
    hipLaunchKernelGGL(gather_kernel, dim3(TOTNATOM / ABLK), dim3(256), 0, stream,
                       cnt8, rec, centers, widths, c_emb, tv_part, dens_bf, tvv);
    hipLaunchKernelGGL(nnm_kernel, dim3(TOTNATOM / 16), dim3(256), 0, stream,
                       dens_bf, tvv, W1, b1, W2, b2, dipole);
}

// Round 18
// 61.675 us; speedup vs baseline: 1.0436x; 1.0436x over previous
//
#include <hip/hip_runtime.h>

#define NMOL   32
#define NATOM  512
#define NPAIR  32768
#define NB     64
#define HIDDEN 256
#define TOTNATOM (NMOL * NATOM)
#define NSUB   16    // sub-blocks per molecule (2x scatter occupancy vs 8)
#define CAPS   12    // records per (atom, sub): lambda~1.14, P(>=12)~1e-10
#define ABLK   16    // atoms per gnn block
#define SLOTS  128   // LDS record slots per atom

typedef __attribute__((ext_vector_type(8))) short bf16x8;
typedef __attribute__((ext_vector_type(4))) float f32x4;

__device__ __forceinline__ unsigned short f2bf(float x) {   // RNE f32->bf16
    unsigned u = __float_as_uint(x);
    u += 0x7FFFu + ((u >> 16) & 1u);
    return (unsigned short)(u >> 16);
}

// ---------------------------------------------------------------------------
// K1 scatter: 512 blocks (mol x sub16) x 1024 thr, 2 pairs/thread.
// LDS-staged cart/species (R16's L1-direct read regressed). NSUB 16 ->
// 2 blocks/CU -> 32 waves/CU. Block 0 zeroes dipole.
// ---------------------------------------------------------------------------
__global__ __launch_bounds__(1024) void scatter_kernel(
    const float* __restrict__ cart, const float* __restrict__ shifts,
    const int* __restrict__ species, const int* __restrict__ atom_index,
    unsigned* __restrict__ cnt, float2* __restrict__ rec,
    float* __restrict__ tv_part, float* __restrict__ dipole, int ndip)
{
    __shared__ float    tv_sc[NATOM * 3];   // 6 KB
    __shared__ float    s_cart[NATOM * 3];  // 6 KB
    __shared__ int      s_sp[NATOM];        // 2 KB
    __shared__ unsigned lcnt[NATOM];        // 2 KB
    const int tid = threadIdx.x;
    const int b   = blockIdx.x;
    const int mol = b >> 4;
    const int sub = b & 15;

    if (b == 0 && tid < ndip) dipole[tid] = 0.f;

    const float* cm = cart + (size_t)mol * NATOM * 3;
    const int*   sp = species + (size_t)mol * NATOM;
    for (int i = tid; i < NATOM * 3; i += 1024) { tv_sc[i] = 0.f; s_cart[i] = cm[i]; }
    if (tid < NATOM) { lcnt[tid] = 0u; s_sp[tid] = sp[tid]; }
    __syncthreads();

    const int* ai0 = atom_index + (size_t)mol * NPAIR;
    const int* ai1 = ai0 + (size_t)NMOL * NPAIR;
    const float* sh = shifts + (size_t)mol * NPAIR * 3;
    const int base = sub * 2048;

#pragma unroll
    for (int k = 0; k < 2; ++k) {
        const int p  = base + k * 1024 + tid;
        const int i0 = ai0[p];
        const int i1 = ai1[p];
        const float sx = sh[p * 3 + 0], sy = sh[p * 3 + 1], sz = sh[p * 3 + 2];
        if (!(sx > -1e10f && sy > -1e10f && sz > -1e10f)) continue;  // masked
        const float dx = s_cart[i0 * 3 + 0] - s_cart[i1 * 3 + 0] + sx;
        const float dy = s_cart[i0 * 3 + 1] - s_cart[i1 * 3 + 1] + sy;
        const float dz = s_cart[i0 * 3 + 2] - s_cart[i1 * 3 + 2] + sz;
        unsafeAtomicAdd(&tv_sc[i0 * 3 + 0], dx);        // ds_add_f32
        unsafeAtomicAdd(&tv_sc[i0 * 3 + 1], dy);
        unsafeAtomicAdd(&tv_sc[i0 * 3 + 2], dz);
        const float d = sqrtf(dx * dx + dy * dy + dz * dz + 1e-12f);
        if (d < 5.0f) {
            const float fc = 0.5f * (__cosf(0.62831853071795864769f * d) + 1.f);
            // pack spc into fc's low 3 mantissa bits (<=2^-20 rel perturbation)
            const unsigned fb = (__float_as_uint(fc) & ~7u) | (unsigned)s_sp[i1];
            const unsigned pos = atomicAdd(&lcnt[i0], 1u);   // LDS, native
            if (pos < CAPS)
                rec[((size_t)b * NATOM + i0) * CAPS + pos] =
                    make_float2(d, __uint_as_float(fb));
        }
    }
    __syncthreads();

    if (tid < NATOM) cnt[((size_t)mol * NATOM + tid) * NSUB + sub] = lcnt[tid];
    float* tg = tv_part + (size_t)b * NATOM * 3;
    for (int i = tid; i < NATOM * 3; i += 1024) tg[i] = tv_sc[i];
}

// ---------------------------------------------------------------------------
// K2 gnn2: gather + MFMA-nn fused, 1024 blocks x 512 thr (8 waves), 16
// atoms/block. ~61KB LDS -> 2 blk/CU x 8 waves = 16 waves/CU (2x R15).
// R17 BUG FIXED: b1/w2 staging used `tid >= 512` with blockDim 512 -- never
// true, b1_l/w2_l were garbage. Now plain `tid < HIDDEN` (overlap is fine).
// ---------------------------------------------------------------------------
__global__ __launch_bounds__(512) void gnn2_kernel(
    const unsigned* __restrict__ cnt, const float2* __restrict__ rec,
    const float* __restrict__ centers, const float* __restrict__ widths,
    const float* __restrict__ c_emb, const float* __restrict__ tv_part,
    const float* __restrict__ W1, const float* __restrict__ b1,
    const float* __restrict__ W2, const float* __restrict__ b2,
    float* __restrict__ dipole)
{
    __shared__ float    cemb[8 * NB];                       // 2 KB
    __shared__ float2   list[ABLK][SLOTS];                  // 16 KB
    __shared__ unsigned scnt[ABLK][NSUB];                   // 1 KB
    __shared__ unsigned soff[ABLK][NSUB];                   // 1 KB
    __shared__ unsigned mtot[ABLK];
    __shared__ __align__(16) unsigned short w1t[HIDDEN * 72];   // 36 KB
    __shared__ __align__(16) unsigned short dens_bf[ABLK][72];  // 2.25 KB
    __shared__ float    b1_l[HIDDEN], w2_l[HIDDEN];         // 2 KB
    __shared__ float    tv_l[ABLK * 3];
    __shared__ float    sred[8][4][4];                      // [wave][fg][i]

    const int tid = threadIdx.x;
    const int a0  = blockIdx.x * ABLK;
    const int mol = a0 >> 9;
    const int ra0 = a0 & 511;

    // ---- phase A: stage everything ----
    if (tid < 8 * NB) cemb[tid] = c_emb[tid];
    for (int i = tid; i < NB * HIDDEN; i += 512) {      // W1^T as bf16, pad 72
        const int k = i >> 8, j = i & 255;              // coalesced f32 reads
        w1t[j * 72 + k] = f2bf(W1[i]);
    }
    if (tid < HIDDEN) { b1_l[tid] = b1[tid]; w2_l[tid] = W2[tid]; }   // FIXED
    if (tid < ABLK * NSUB) {                            // 256 counts
        const int al = tid >> 4, s = tid & 15;
        scnt[al][s] = cnt[(size_t)(a0 + al) * NSUB + s];
    }
    if (tid < ABLK * 3) {                               // tv partial sums
        const int al = tid / 3, c = tid - al * 3;
        float s = 0.f;
#pragma unroll
        for (int sb = 0; sb < NSUB; ++sb)
            s += tv_part[((size_t)(mol * NSUB + sb) * NATOM + (ra0 + al)) * 3 + c];
        tv_l[al * 3 + c] = s;
    }
    __syncthreads();

    if (tid < ABLK) {    // per-atom prefix over 16 segment counts + zero-pad
        int o = 0;
#pragma unroll
        for (int s = 0; s < NSUB; ++s) {
            soff[tid][s] = (unsigned)o;
            o += min((int)scnt[tid][s], CAPS);
        }
        if (o > SLOTS) o = SLOTS;                       // paranoia clamp
        const int mp = (o + 7) & ~7;                    // pad to multiple of 8
        mtot[tid] = (unsigned)mp;
        for (int k = o; k < mp; ++k) list[tid][k] = make_float2(0.f, 0.f);
    }
    __syncthreads();

    {   // parallel segment copy: 2 threads per (atom, sub) segment (256 segs)
        const int seg = tid >> 1;                       // 0..255
        const int prt = tid & 1;
        const int al = seg >> 4, s = seg & 15;
        const int off = (int)soff[al][s];
        int n = min((int)scnt[al][s], CAPS);
        n = min(n, SLOTS - off);                        // clamp (paranoia)
        const float2* src = rec + ((size_t)(mol * NSUB + s) * NATOM + (ra0 + al)) * CAPS;
        float2* dst = &list[al][off];
        const int k0 = prt * 6, k1 = min(k0 + 6, n);
        for (int k = k0; k < k1; ++k) dst[k] = src[k];
    }
    __syncthreads();

    const int lane = tid & 63;
    const int wave = tid >> 6;                          // 0..7

    // ---- phase B: gather (wave = 2 atoms, lane = basis) ----
    {
        const float cb   = centers[lane];
        const float nwb2 = -widths[lane] * 1.4426950408889634f;  // fold log2(e)

#define REC1(A, dv, fv) { const unsigned f_ = __float_as_uint(fv);           \
        const float t_ = (dv) - cb;                                          \
        A = fmaf(exp2f(nwb2 * t_ * t_) * __uint_as_float(f_ & ~7u),          \
                 cemb[((f_ & 7u) << 6) | lane], A); }

        for (int al = wave; al < ABLK; al += 8) {
            const int m = (int)mtot[al];
            const float4* l4 = reinterpret_cast<const float4*>(list[al]);
            float acc0 = 0.f, acc1 = 0.f;
            for (int j = 0; j < m; j += 8) {
                const float4 q0 = l4[(j >> 1) + 0];
                const float4 q1 = l4[(j >> 1) + 1];
                const float4 q2 = l4[(j >> 1) + 2];
                const float4 q3 = l4[(j >> 1) + 3];
                REC1(acc0, q0.x, q0.y) REC1(acc1, q0.z, q0.w)
                REC1(acc0, q1.x, q1.y) REC1(acc1, q1.z, q1.w)
                REC1(acc0, q2.x, q2.y) REC1(acc1, q2.z, q2.w)
                REC1(acc0, q3.x, q3.y) REC1(acc1, q3.z, q3.w)
            }
            dens_bf[al][lane] = f2bf(acc0 + acc1);
        }
#undef REC1
    }
    __syncthreads();

    // ---- phase C: MFMA nn. 16-atom M-tile shared; wave covers 2 N-tiles ----
    {
        const int fr = lane & 15;      // C col (j in tile) / A-B row
        const int fg = lane >> 4;      // k-group; C rows = fg*4+i

        bf16x8 afr[2];
#pragma unroll
        for (int kk = 0; kk < 2; ++kk)
            afr[kk] = *reinterpret_cast<const bf16x8*>(
                &dens_bf[fr][kk * 32 + fg * 8]);

        float sdip[4] = {0.f, 0.f, 0.f, 0.f};
#pragma unroll
        for (int t = 0; t < 2; ++t) {
            const int nt = wave * 2 + t;
            const bf16x8 bf0 = *reinterpret_cast<const bf16x8*>(
                &w1t[(nt * 16 + fr) * 72 + 0 + fg * 8]);
            const bf16x8 bf1 = *reinterpret_cast<const bf16x8*>(
                &w1t[(nt * 16 + fr) * 72 + 32 + fg * 8]);
            f32x4 acc = {0.f, 0.f, 0.f, 0.f};
            acc = __builtin_amdgcn_mfma_f32_16x16x32_bf16(afr[0], bf0, acc, 0, 0, 0);
            acc = __builtin_amdgcn_mfma_f32_16x16x32_bf16(afr[1], bf1, acc, 0, 0, 0);
            const int j = nt * 16 + fr;
            const float b1v = b1_l[j], w2v = w2_l[j];
#pragma unroll
            for (int i = 0; i < 4; ++i) {               // silu * W2
                const float h = acc[i] + b1v;
                sdip[i] += (h / (1.f + __expf(-h))) * w2v;
            }
        }
#pragma unroll
        for (int off = 1; off < 16; off <<= 1) {        // reduce over 16 j-cols
#pragma unroll
            for (int i = 0; i < 4; ++i) sdip[i] += __shfl_xor(sdip[i], off);
        }
        if (fr == 0) {
#pragma unroll
            for (int i = 0; i < 4; ++i) sred[wave][fg][i] = sdip[i];
        }
        __syncthreads();

        if (tid < ABLK) {                               // atom a = tid
            const int a = tid;
            float out = b2[0];
#pragma unroll
            for (int w = 0; w < 8; ++w) out += sred[w][a >> 2][a & 3];
            float px = out * tv_l[a * 3 + 0];
            float py = out * tv_l[a * 3 + 1];
            float pz = out * tv_l[a * 3 + 2];
#pragma unroll
            for (int off = 8; off; off >>= 1) {
                px += __shfl_down(px, off, 16);
                py += __shfl_down(py, off, 16);
                pz += __shfl_down(pz, off, 16);
            }
            if (a == 0) {
                unsafeAtomicAdd(&dipole[mol * 3 + 0], px);
                unsafeAtomicAdd(&dipole[mol * 3 + 1], py);
                unsafeAtomicAdd(&dipole[mol * 3 + 2], pz);
            }
        }
    }
}

// ---------------------------------------------------------------------------
extern "C" void kernel_launch(void* const* d_in, const int* in_sizes, int n_in,
                              void* d_out, int out_size, void* d_ws, size_t ws_size,
                              hipStream_t stream)
{
    const float* cart       = (const float*)d_in[0];
    const float* shifts     = (const float*)d_in[1];
    const float* centers    = (const float*)d_in[2];
    const float* widths     = (const float*)d_in[3];
    const float* c_emb      = (const float*)d_in[4];
    const float* W1         = (const float*)d_in[5];
    const float* b1         = (const float*)d_in[6];
    const float* W2         = (const float*)d_in[7];
    const float* b2         = (const float*)d_in[8];
    const int*   species    = (const int*)d_in[10];
    const int*   atom_index = (const int*)d_in[11];

    // ws: tv_part(3MB) | cnt(1MB) | rec(25MB)
    float*    tv_part = (float*)d_ws;
    unsigned* cnt     = (unsigned*)(tv_part + (size_t)NMOL * NSUB * NATOM * 3);
    float2*   rec     = (float2*)(cnt + (size_t)TOTNATOM * NSUB);
    float*    dipole  = (float*)d_out;

    hipLaunchKernelGGL(scatter_kernel, dim3(NMOL * NSUB), dim3(1024), 0, stream,
                       cart, shifts, species, atom_index, cnt, rec, tv_part,
                       dipole, out_size);
    hipLaunchKernelGGL(gnn2_kernel, dim3(TOTNATOM / ABLK), dim3(512), 0, stream,
                       cnt, rec, centers, widths, c_emb, tv_part,
                       W1, b1, W2, b2, dipole);
}

// Round 19
// 55.867 us; speedup vs baseline: 1.1521x; 1.1040x over previous
//
#include <hip/hip_runtime.h>

#define NMOL   32
#define NATOM  512
#define NPAIR  32768
#define NB     64
#define HIDDEN 256
#define TOTNATOM (NMOL * NATOM)
#define NSUB   8
#define BLKCAP 2560   // records per block region (mean 1065, sigma 28: +53 sigma)
#define ABLK   8      // atoms per gather block
#define SLOTS  128    // LDS record slots per atom in gather

typedef __attribute__((ext_vector_type(8))) short bf16x8;
typedef __attribute__((ext_vector_type(4))) float f32x4;

__device__ __forceinline__ unsigned short f2bf(float x) {   // RNE f32->bf16
    unsigned u = __float_as_uint(x);
    u += 0x7FFFu + ((u >> 16) & 1u);
    return (unsigned short)(u >> 16);
}

// ---------------------------------------------------------------------------
// K1 scatter: 256 blocks (mol x sub8) x 1024 thr, 4 pairs/thread.
// R19: records placed atom-grouped in LDS (pass1 count -> prefix scan ->
// pass2 place), then ONE COALESCED sweep to a contiguous per-block region.
// Kills the scattered-bucket HBM stores (R6 counter evidence: 52MB WRITE for
// 16MB payload = ~3x line amplification; est ~10us of R14's ~15us scatter).
// Also removes per-bucket CAP truncation (exact counts).
// ---------------------------------------------------------------------------
__global__ __launch_bounds__(1024) void scatter_kernel(
    const float* __restrict__ cart, const float* __restrict__ shifts,
    const int* __restrict__ species, const int* __restrict__ atom_index,
    unsigned* __restrict__ cnt, unsigned* __restrict__ soff_g,
    float2* __restrict__ rec, float* __restrict__ tv_part)
{
    __shared__ float    tv_sc[NATOM * 3];   // 6 KB
    __shared__ float    s_cart[NATOM * 3];  // 6 KB
    __shared__ int      s_sp[NATOM];        // 2 KB
    __shared__ unsigned lcnt[NATOM];        // 2 KB (exact per-atom counts)
    __shared__ unsigned inc[NATOM];         // 2 KB (inclusive scan)
    __shared__ unsigned pcnt[NATOM];        // 2 KB (pass-2 cursors)
    __shared__ float2   list[BLKCAP];       // 20 KB (atom-grouped records)

    const int tid = threadIdx.x;
    const int b   = blockIdx.x;
    const int mol = b >> 3;
    const int sub = b & 7;

    const float* cm = cart + (size_t)mol * NATOM * 3;
    const int*   sp = species + (size_t)mol * NATOM;
    for (int i = tid; i < NATOM * 3; i += 1024) { tv_sc[i] = 0.f; s_cart[i] = cm[i]; }
    if (tid < NATOM) { lcnt[tid] = 0u; pcnt[tid] = 0u; s_sp[tid] = sp[tid]; }
    __syncthreads();

    const int* ai0 = atom_index + (size_t)mol * NPAIR;
    const int* ai1 = ai0 + (size_t)NMOL * NPAIR;
    const float* sh = shifts + (size_t)mol * NPAIR * 3;
    const int base = sub * 4096;

    // pass 1: compute, tv atomics, count; cache {d, fb, i0} in registers
    float    rd[4];
    unsigned rf[4];
    int      ri[4];
#pragma unroll
    for (int k = 0; k < 4; ++k) {
        ri[k] = -1;
        const int p  = base + k * 1024 + tid;
        const int i0 = ai0[p];
        const int i1 = ai1[p];
        const float sx = sh[p * 3 + 0], sy = sh[p * 3 + 1], sz = sh[p * 3 + 2];
        if (!(sx > -1e10f && sy > -1e10f && sz > -1e10f)) continue;  // masked
        const float dx = s_cart[i0 * 3 + 0] - s_cart[i1 * 3 + 0] + sx;
        const float dy = s_cart[i0 * 3 + 1] - s_cart[i1 * 3 + 1] + sy;
        const float dz = s_cart[i0 * 3 + 2] - s_cart[i1 * 3 + 2] + sz;
        unsafeAtomicAdd(&tv_sc[i0 * 3 + 0], dx);        // ds_add_f32
        unsafeAtomicAdd(&tv_sc[i0 * 3 + 1], dy);
        unsafeAtomicAdd(&tv_sc[i0 * 3 + 2], dz);
        const float d = sqrtf(dx * dx + dy * dy + dz * dz + 1e-12f);
        if (d < 5.0f) {
            const float fc = 0.5f * (__cosf(0.62831853071795864769f * d) + 1.f);
            // pack spc into fc's low 3 mantissa bits (<=2^-20 rel perturbation)
            rd[k] = d;
            rf[k] = (__float_as_uint(fc) & ~7u) | (unsigned)s_sp[i1];
            ri[k] = i0;
            atomicAdd(&lcnt[i0], 1u);                   // LDS, native
        }
    }
    __syncthreads();

    // inclusive Hillis-Steele scan of lcnt -> inc (512 entries)
    if (tid < NATOM) inc[tid] = lcnt[tid];
    __syncthreads();
#pragma unroll
    for (int off = 1; off < NATOM; off <<= 1) {
        unsigned v = 0;
        if (tid < NATOM && tid >= off) v = inc[tid - off];
        __syncthreads();
        if (tid < NATOM) inc[tid] += v;
        __syncthreads();
    }

    // pass 2: place records atom-grouped in LDS
#pragma unroll
    for (int k = 0; k < 4; ++k) {
        if (ri[k] >= 0) {
            const unsigned exc = inc[ri[k]] - lcnt[ri[k]];   // exclusive offset
            const unsigned pos = atomicAdd(&pcnt[ri[k]], 1u);
            const unsigned idx = exc + pos;
            if (idx < (unsigned)BLKCAP)
                list[idx] = make_float2(rd[k], __uint_as_float(rf[k]));
        }
    }
    __syncthreads();

    // coalesced sweep: LDS list -> contiguous per-block region
    const int tot = min((int)inc[NATOM - 1], BLKCAP);
    float2* dstr = rec + (size_t)b * BLKCAP;
    for (int i = tid; i < tot; i += 1024) dstr[i] = list[i];

    if (tid < NATOM) {
        cnt[((size_t)mol * NATOM + tid) * NSUB + sub] = lcnt[tid];
        soff_g[(size_t)b * NATOM + tid] = inc[tid] - lcnt[tid];
    }
    float* tg = tv_part + (size_t)b * NATOM * 3;
    for (int i = tid; i < NATOM * 3; i += 1024) tg[i] = tv_sc[i];
}

// ---------------------------------------------------------------------------
// K2 gather: 2048 blocks x 256 thr, 8 atoms/block (R14 structure; only the
// rec addressing changed: segment = rec[b*BLKCAP + soff_g[b][atom]]).
// Emits density as BF16 rows + summed tv.
// ---------------------------------------------------------------------------
__global__ __launch_bounds__(256) void gather_kernel(
    const unsigned* __restrict__ cnt, const unsigned* __restrict__ soff_g,
    const float2* __restrict__ rec,
    const float* __restrict__ centers, const float* __restrict__ widths,
    const float* __restrict__ c_emb, const float* __restrict__ tv_part,
    unsigned short* __restrict__ dens_bf, float* __restrict__ tvv)
{
    __shared__ float    cemb[8 * NB];          // 2 KB
    __shared__ float2   list[ABLK][SLOTS];     // 8 KB
    __shared__ unsigned scnt[ABLK][NSUB];
    __shared__ unsigned sofg[ABLK][NSUB];
    __shared__ unsigned soff[ABLK][NSUB];
    __shared__ unsigned mtot[ABLK];

    const int tid = threadIdx.x;
    const int a0  = blockIdx.x * ABLK;
    const int mol = a0 >> 9;
    const int ra0 = a0 & 511;

    for (int i = tid; i < 8 * NB; i += 256) cemb[i] = c_emb[i];
    if (tid < ABLK * NSUB) {
        const int al = tid >> 3, s = tid & 7;
        scnt[al][s] = cnt[(size_t)(a0 + al) * NSUB + s];
        sofg[al][s] = soff_g[(size_t)(mol * NSUB + s) * NATOM + (ra0 + al)];
    }
    __syncthreads();

    if (tid < ABLK) {    // per-atom prefix over 8 segment counts + zero-pad
        int o = 0;
#pragma unroll
        for (int s = 0; s < NSUB; ++s) {
            soff[tid][s] = (unsigned)o;
            o += min((int)scnt[tid][s], SLOTS - o);
        }
        const int mp = (o + 7) & ~7;           // pad to multiple of 8
        mtot[tid] = (unsigned)mp;
        for (int k = o; k < mp; ++k) list[tid][k] = make_float2(0.f, 0.f);
    }
    __syncthreads();

    {   // 256-thread parallel segment copy: 4 threads per (atom, sub) segment
        const int seg = tid >> 2;              // 0..63
        const int prt = tid & 3;
        const int al = seg >> 3, s = seg & 7;
        const int off = (int)soff[al][s];
        const int n = min((int)scnt[al][s], SLOTS - off);
        const float2* src = rec + (size_t)(mol * NSUB + s) * BLKCAP + sofg[al][s];
        float2* dst = &list[al][off];
        const int k0 = prt * 5, k1 = min(k0 + 5, n);
        for (int k = k0; k < k1; ++k) dst[k] = src[k];
    }
    if (tid < ABLK * 3) {                      // tv: sum the 8 block-partials
        const int al = tid / 3, c = tid - al * 3;
        float s = 0.f;
#pragma unroll
        for (int sb = 0; sb < NSUB; ++sb)
            s += tv_part[((size_t)(mol * NSUB + sb) * NATOM + (ra0 + al)) * 3 + c];
        tvv[(size_t)(a0 + al) * 3 + c] = s;
    }
    __syncthreads();

    const int lane = tid & 63;
    const int wave = tid >> 6;
    const float cb   = centers[lane];
    const float nwb2 = -widths[lane] * 1.4426950408889634f;   // fold log2(e)

#define REC1(A, dv, fv) { const unsigned f_ = __float_as_uint(fv);           \
        const float t_ = (dv) - cb;                                          \
        A = fmaf(exp2f(nwb2 * t_ * t_) * __uint_as_float(f_ & ~7u),          \
                 cemb[((f_ & 7u) << 6) | lane], A); }

    for (int al = wave; al < ABLK; al += 4) {  // wave handles 2 atoms
        const int m = (int)mtot[al];
        const float4* l4 = reinterpret_cast<const float4*>(list[al]);
        float acc0 = 0.f, acc1 = 0.f;
        for (int j = 0; j < m; j += 8) {
            const float4 q0 = l4[(j >> 1) + 0];
            const float4 q1 = l4[(j >> 1) + 1];
            const float4 q2 = l4[(j >> 1) + 2];
            const float4 q3 = l4[(j >> 1) + 3];
            REC1(acc0, q0.x, q0.y) REC1(acc1, q0.z, q0.w)
            REC1(acc0, q1.x, q1.y) REC1(acc1, q1.z, q1.w)
            REC1(acc0, q2.x, q2.y) REC1(acc1, q2.z, q2.w)
            REC1(acc0, q3.x, q3.y) REC1(acc1, q3.z, q3.w)
        }
        dens_bf[(size_t)(a0 + al) * NB + lane] = f2bf(acc0 + acc1);
    }
#undef REC1
}

// ---------------------------------------------------------------------------
// K3 nn via MFMA: 256 blocks x 256 thr; block = 64 atoms (verbatim R14 --
// best measured config). Partial dipole per block.
// ---------------------------------------------------------------------------
__global__ __launch_bounds__(256) void nn_kernel(
    const unsigned short* __restrict__ dens_bf, const float* __restrict__ tvv,
    const float* __restrict__ W1, const float* __restrict__ b1,
    const float* __restrict__ W2, const float* __restrict__ b2,
    float* __restrict__ dip_part)
{
    __shared__ __align__(16) unsigned short w1t[HIDDEN * 72];  // 36 KB
    __shared__ float b1_l[HIDDEN], w2_l[HIDDEN];
    __shared__ float sred[4][4][3];

    const int tid = threadIdx.x;

    for (int i = tid; i < NB * HIDDEN; i += 256) {     // stage W1^T as bf16
        const int k = i >> 8, j = i & 255;             // coalesced f32 reads
        w1t[j * 72 + k] = f2bf(W1[i]);
    }
    if (tid < HIDDEN) { b1_l[tid] = b1[tid]; w2_l[tid] = W2[tid]; }
    __syncthreads();

    const int lane = tid & 63;
    const int wave = tid >> 6;
    const int fr   = lane & 15;        // frag row (atom) / col (j) index
    const int fg   = lane >> 4;        // frag k-group
    const int a0w  = blockIdx.x * 64 + wave * 16;      // wave's 16 atoms

    bf16x8 afr[2];
#pragma unroll
    for (int kk = 0; kk < 2; ++kk)
        afr[kk] = *reinterpret_cast<const bf16x8*>(
            dens_bf + (size_t)(a0w + fr) * NB + kk * 32 + fg * 8);

    float sdip[4] = {0.f, 0.f, 0.f, 0.f};
#pragma unroll
    for (int nt = 0; nt < 16; ++nt) {                  // N-tiles of 16 j's
        const bf16x8 bf0 = *reinterpret_cast<const bf16x8*>(
            &w1t[(nt * 16 + fr) * 72 + 0 + fg * 8]);
        const bf16x8 bf1 = *reinterpret_cast<const bf16x8*>(
            &w1t[(nt * 16 + fr) * 72 + 32 + fg * 8]);
        f32x4 acc = {0.f, 0.f, 0.f, 0.f};
        acc = __builtin_amdgcn_mfma_f32_16x16x32_bf16(afr[0], bf0, acc, 0, 0, 0);
        acc = __builtin_amdgcn_mfma_f32_16x16x32_bf16(afr[1], bf1, acc, 0, 0, 0);
        const int j = nt * 16 + fr;                    // this lane's column
        const float b1v = b1_l[j], w2v = w2_l[j];
#pragma unroll
        for (int i = 0; i < 4; ++i) {                  // silu * W2, accumulate
            const float h = acc[i] + b1v;
            sdip[i] += (h / (1.f + __expf(-h))) * w2v;
        }
    }
#pragma unroll
    for (int off = 1; off < 16; off <<= 1) {           // reduce over j-cols
#pragma unroll
        for (int i = 0; i < 4; ++i) sdip[i] += __shfl_xor(sdip[i], off);
    }
    if (fr == 0) {                                     // rows a0w + fg*4 + i
        const float b2v = b2[0];
        float px = 0.f, py = 0.f, pz = 0.f;
#pragma unroll
        for (int i = 0; i < 4; ++i) {
            const int a = a0w + fg * 4 + i;
            const float out = sdip[i] + b2v;
            px += out * tvv[a * 3 + 0];
            py += out * tvv[a * 3 + 1];
            pz += out * tvv[a * 3 + 2];
        }
        sred[wave][fg][0] = px; sred[wave][fg][1] = py; sred[wave][fg][2] = pz;
    }
    __syncthreads();
    if (tid < 3) {
        float s = 0.f;
#pragma unroll
        for (int w = 0; w < 4; ++w)
#pragma unroll
            for (int g = 0; g < 4; ++g) s += sred[w][g][tid];
        dip_part[blockIdx.x * 3 + tid] = s;
    }
}

// ---------------------------------------------------------------------------
// K4 dipfinal: 8 nn-block partials per molecule (verbatim R14).
// ---------------------------------------------------------------------------
__global__ __launch_bounds__(128) void dipfinal_kernel(
    const float* __restrict__ dip_part, float* __restrict__ dipole)
{
    const int t = threadIdx.x;
    if (t < NMOL * 3) {
        const int m = t / 3, c = t - m * 3;
        float s = 0.f;
#pragma unroll
        for (int k = 0; k < 8; ++k) s += dip_part[(m * 8 + k) * 3 + c];
        dipole[t] = s;
    }
}

// ---------------------------------------------------------------------------
extern "C" void kernel_launch(void* const* d_in, const int* in_sizes, int n_in,
                              void* d_out, int out_size, void* d_ws, size_t ws_size,
                              hipStream_t stream)
{
    const float* cart       = (const float*)d_in[0];
    const float* shifts     = (const float*)d_in[1];
    const float* centers    = (const float*)d_in[2];
    const float* widths     = (const float*)d_in[3];
    const float* c_emb      = (const float*)d_in[4];
    const float* W1         = (const float*)d_in[5];
    const float* b1         = (const float*)d_in[6];
    const float* W2         = (const float*)d_in[7];
    const float* b2         = (const float*)d_in[8];
    const int*   species    = (const int*)d_in[10];
    const int*   atom_index = (const int*)d_in[11];

    // ws: tv_part(1.5MB) | cnt(512KB) | soff_g(512KB) | dip_part(3KB) |
    //     tvv(192KB) | dens_bf(2MB) | rec(5MB)
    float*          tv_part  = (float*)d_ws;
    unsigned*       cnt      = (unsigned*)(tv_part + (size_t)NMOL * NSUB * NATOM * 3);
    unsigned*       soff_g   = cnt + (size_t)TOTNATOM * NSUB;
    float*          dip_part = (float*)(soff_g + (size_t)NMOL * NSUB * NATOM);
    float*          tvv      = dip_part + 256 * 3;
    unsigned short* dens_bf  = (unsigned short*)(tvv + (size_t)TOTNATOM * 3);
    float2*         rec      = (float2*)(dens_bf + (size_t)TOTNATOM * NB);
    float*          dipole   = (float*)d_out;

    hipLaunchKernelGGL(scatter_kernel, dim3(NMOL * NSUB), dim3(1024), 0, stream,
                       cart, shifts, species, atom_index, cnt, soff_g, rec, tv_part);
    hipLaunchKernelGGL(gather_kernel, dim3(TOTNATOM / ABLK), dim3(256), 0, stream,
                       cnt, soff_g, rec, centers, widths, c_emb, tv_part,
                       dens_bf, tvv);
    hipLaunchKernelGGL(nn_kernel, dim3(TOTNATOM / 64), dim3(256), 0, stream,
                       dens_bf, tvv, W1, b1, W2, b2, dip_part);
    hipLaunchKernelGGL(dipfinal_kernel, dim3(1), dim3(128), 0, stream,
                       dip_part, dipole);
}